// Round 3
// baseline (587.165 us; speedup 1.0000x reference)
//
#include <hip/hip_runtime.h>

typedef __attribute__((ext_vector_type(8))) short short8;
typedef __attribute__((ext_vector_type(4))) float v4f;

#define S_SP 16384

__device__ inline float bf2f(unsigned short u) {
  union { unsigned int i; float f; } v; v.i = ((unsigned int)u) << 16; return v.f;
}
__device__ inline unsigned short f2bf(float f) {
  union { float f; unsigned int i; } v; v.f = f;
  unsigned int u = v.i;
  return (unsigned short)((u + 0x7FFFu + ((u >> 16) & 1u)) >> 16);
}

// ---- weight repack: Wr[o][t*128+c] = bf16(w[o][c][t]); bias fp32 copy --------
__global__ __launch_bounds__(256) void repack_kernel(
    const float* __restrict__ wq, const float* __restrict__ wk,
    const float* __restrict__ wv, const float* __restrict__ wp,
    const float* __restrict__ bq, const float* __restrict__ bk,
    const float* __restrict__ bv, const float* __restrict__ bp,
    unsigned short* __restrict__ Wr, float* __restrict__ biasf)
{
  int i = blockIdx.x * 256 + threadIdx.x;
  const int WN = 4 * 49152;
  if (i < WN) {
    int m = i / 49152;
    int r = i % 49152;
    int o = r / 384, k = r % 384;
    int t = k >> 7, c = k & 127;
    const float* w = (m == 0) ? wq : (m == 1) ? wk : (m == 2) ? wv : wp;
    Wr[i] = f2bf(w[o * 384 + c * 3 + t]);
  } else if (i < WN + 512) {
    int j = i - WN;
    int m = j >> 7, o = j & 127;
    const float* bb = (m == 0) ? bq : (m == 1) ? bk : (m == 2) ? bv : bp;
    biasf[j] = bb[o];
  }
}

// ---- ingress: fp32 [R][C] -> bf16 [C][R], per z-slice (R=128, C=16384) -------
__global__ __launch_bounds__(256) void transpose_f2b_kernel(
    const float* __restrict__ in, unsigned short* __restrict__ out,
    int R, int C)
{
  __shared__ unsigned short t[64][72];
  int tid = threadIdx.x;
  size_t slice = blockIdx.z;
  const float* ip = in + slice * (size_t)R * C;
  unsigned short* op = out + slice * (size_t)R * C;
  int c0 = blockIdx.x * 64, r0 = blockIdx.y * 64;
#pragma unroll
  for (int p = 0; p < 4; ++p) {
    int id = tid + p * 256;
    int row = id >> 4, col = (id & 15) * 4;
    float4 v = *(const float4*)(ip + (size_t)(r0 + row) * C + c0 + col);
    t[row][col + 0] = f2bf(v.x);
    t[row][col + 1] = f2bf(v.y);
    t[row][col + 2] = f2bf(v.z);
    t[row][col + 3] = f2bf(v.w);
  }
  __syncthreads();
#pragma unroll
  for (int p = 0; p < 2; ++p) {
    int id = tid + p * 256;
    int crow = id >> 3, rcol = (id & 7) * 8;
    uint4 v;
    v.x = (unsigned)t[rcol + 0][crow] | ((unsigned)t[rcol + 1][crow] << 16);
    v.y = (unsigned)t[rcol + 2][crow] | ((unsigned)t[rcol + 3][crow] << 16);
    v.z = (unsigned)t[rcol + 4][crow] | ((unsigned)t[rcol + 5][crow] << 16);
    v.w = (unsigned)t[rcol + 6][crow] | ((unsigned)t[rcol + 7][crow] << 16);
    *(uint4*)(op + (size_t)(c0 + crow) * R + r0 + rcol) = v;
  }
}

// ---- conv: stage full K=384 B-panel once; weights direct from L2; z-loop -----
// B LDS layout: Bl[s_local][392] (pitch 392 shorts = 49 x 16B granules -> 2-way max)
// out bf16: outB[z][slice][s][o]; out fp32: outF[slice][o][s] (= d_out layout)
template<int NZ, bool F32OUT>
__global__ __launch_bounds__(256) void conv_kernel(
    const unsigned short* __restrict__ inT,
    const unsigned short* __restrict__ Wr_all,
    const float* __restrict__ bias_all,
    unsigned short* __restrict__ outB,
    float* __restrict__ outF)
{
  __shared__ unsigned short Bl[64 * 392];
  int tid = threadIdx.x;
  int s0 = blockIdx.x * 64;
  int slice = blockIdx.y;
  int b = slice >> 3, l = slice & 7;
  int half4 = (l >> 2) << 2;

  // ---- stage: 64 s x 384 k (3 taps), one pass, edge taps zeroed -------------
#pragma unroll
  for (int it = 0; it < 12; ++it) {
    int tap = it >> 2;
    int s_local = ((it & 3) << 4) + (tid >> 4);
    int cg = (tid & 15) << 3;
    int lp = l - 1 + tap;
    uint4 v; v.x = 0; v.y = 0; v.z = 0; v.w = 0;
    if (lp >= half4 && lp <= half4 + 3)
      v = *(const uint4*)(inT + ((size_t)(b * 8 + lp) * S_SP + s0 + s_local) * 128 + cg);
    *(uint4*)(Bl + s_local * 392 + tap * 128 + cg) = v;
  }
  __syncthreads();

  int wave = tid >> 6, lane = tid & 63;
  int quad = lane >> 4, l15 = lane & 15;
  int ob = wave * 32;
  const unsigned short* bbase = Bl + l15 * 392 + quad * 8;

  for (int z = 0; z < NZ; ++z) {
    const unsigned short* Wr = Wr_all + z * 49152;
    const float* bias = bias_all + z * 128;
    const unsigned short* abase = Wr + (size_t)(ob + l15) * 384 + quad * 8;

    v4f acc[2][4];
#pragma unroll
    for (int i = 0; i < 2; ++i)
#pragma unroll
      for (int j = 0; j < 4; ++j)
        acc[i][j] = (v4f){0.f, 0.f, 0.f, 0.f};

    // A prefetch depth 2 (L2-broadcast 16B loads)
    short8 aP0[2], aP1[2];
#pragma unroll
    for (int i = 0; i < 2; ++i) {
      aP0[i] = *(const short8*)(abase + i * 16 * 384);
      aP1[i] = *(const short8*)(abase + i * 16 * 384 + 32);
    }
#pragma unroll
    for (int kc = 0; kc < 12; ++kc) {
      short8 aC[2];
#pragma unroll
      for (int i = 0; i < 2; ++i) { aC[i] = aP0[i]; aP0[i] = aP1[i]; }
      if (kc < 10) {
#pragma unroll
        for (int i = 0; i < 2; ++i)
          aP1[i] = *(const short8*)(abase + i * 16 * 384 + (kc + 2) * 32);
      }
      short8 bfr[4];
#pragma unroll
      for (int j = 0; j < 4; ++j)
        bfr[j] = *(const short8*)(bbase + j * 16 * 392 + kc * 32);
#pragma unroll
      for (int i = 0; i < 2; ++i)
#pragma unroll
        for (int j = 0; j < 4; ++j)
          acc[i][j] = __builtin_amdgcn_mfma_f32_16x16x32_bf16(aC[i], bfr[j], acc[i][j], 0, 0, 0);
    }

    if (!F32OUT) {
      unsigned short* out = outB + (size_t)z * 16 * S_SP * 128 +
                            ((size_t)slice * S_SP + s0) * 128;
#pragma unroll
      for (int i = 0; i < 2; ++i) {
        int obase = ob + i * 16 + quad * 4;
        float4 bb = *(const float4*)(bias + obase);
#pragma unroll
        for (int j = 0; j < 4; ++j) {
          int s_loc = j * 16 + l15;
          uint2 st;
          st.x = (unsigned)f2bf(acc[i][j].x + bb.x) | ((unsigned)f2bf(acc[i][j].y + bb.y) << 16);
          st.y = (unsigned)f2bf(acc[i][j].z + bb.z) | ((unsigned)f2bf(acc[i][j].w + bb.w) << 16);
          *(uint2*)(out + (size_t)s_loc * 128 + obase) = st;
        }
      }
    } else {
      float* out = outF + (size_t)slice * 128 * S_SP + s0;
#pragma unroll
      for (int i = 0; i < 2; ++i) {
        int obase = ob + i * 16 + quad * 4;
        float4 bb = *(const float4*)(bias + obase);
#pragma unroll
        for (int j = 0; j < 4; ++j) {
          int s_loc = j * 16 + l15;
          out[(size_t)(obase + 0) * S_SP + s_loc] = acc[i][j].x + bb.x;
          out[(size_t)(obase + 1) * S_SP + s_loc] = acc[i][j].y + bb.y;
          out[(size_t)(obase + 2) * S_SP + s_loc] = acc[i][j].z + bb.z;
          out[(size_t)(obase + 3) * S_SP + s_loc] = acc[i][j].w + bb.w;
        }
      }
    }
  }
}

// ---- fused both-direction window attention, software-pipelined loads ---------
__device__ inline float dot16(const uint4& a, const uint4& b, const float* q) {
  unsigned v[8] = {a.x, a.y, a.z, a.w, b.x, b.y, b.z, b.w};
  float d = 0.f;
#pragma unroll
  for (int i = 0; i < 8; ++i) {
    d += q[2 * i] * bf2f((unsigned short)(v[i] & 0xffffu));
    d += q[2 * i + 1] * bf2f((unsigned short)(v[i] >> 16));
  }
  return d;
}
__device__ inline void axpy16(const uint4& a, const uint4& b, float p, float* y) {
  unsigned v[8] = {a.x, a.y, a.z, a.w, b.x, b.y, b.z, b.w};
#pragma unroll
  for (int i = 0; i < 8; ++i) {
    y[2 * i] += p * bf2f((unsigned short)(v[i] & 0xffffu));
    y[2 * i + 1] += p * bf2f((unsigned short)(v[i] >> 16));
  }
}

__global__ __launch_bounds__(256) void attn_kernel(
    const unsigned short* __restrict__ QT,
    const unsigned short* __restrict__ KT,
    const unsigned short* __restrict__ VT,
    unsigned short* __restrict__ YT)
{
  int tid = threadIdx.x;
  int wave = tid >> 6, lane = tid & 63;
  int dir = wave & 1;
  int win = blockIdx.x * 2 + (wave >> 1);
  int by = blockIdx.y;
  int b = by >> 2, l0 = by & 3;
  int head = lane >> 3, qi = lane & 7;
  int d0 = win >> 8, h0 = (win >> 4) & 15, w0 = win & 15;
  int lq = l0 + dir * 4;
  int lk = l0 + 4 - dir * 4;
  int sE[8];
#pragma unroll
  for (int e = 0; e < 8; ++e)
    sE[e] = (2 * d0 + (e >> 2)) * 1024 + (2 * h0 + ((e >> 1) & 1)) * 32 + (2 * w0 + (e & 1));

  size_t qbase = ((size_t)(b * 8 + lq) * S_SP + sE[qi]) * 128 + head * 16;
  size_t kslice = (size_t)(b * 8 + lk) * S_SP;

  const unsigned short* qp = QT + qbase;
  uint4 qa = *(const uint4*)qp, qb = *(const uint4*)(qp + 8);
  float q[16];
  {
    unsigned v[8] = {qa.x, qa.y, qa.z, qa.w, qb.x, qb.y, qb.z, qb.w};
#pragma unroll
    for (int i = 0; i < 8; ++i) {
      q[2 * i] = bf2f((unsigned short)(v[i] & 0xffffu));
      q[2 * i + 1] = bf2f((unsigned short)(v[i] >> 16));
    }
  }

  float lg[8];
  uint4 ka, kb;
  {
    const unsigned short* kp = KT + (kslice + sE[0]) * 128 + head * 16;
    ka = *(const uint4*)kp; kb = *(const uint4*)(kp + 8);
  }
#pragma unroll
  for (int j = 0; j < 8; ++j) {
    uint4 na, nb;
    if (j < 7) {
      const unsigned short* kp = KT + (kslice + sE[j + 1]) * 128 + head * 16;
      na = *(const uint4*)kp; nb = *(const uint4*)(kp + 8);
    }
    lg[j] = dot16(ka, kb, q) * 0.25f;  // scale = (C/NH)^-0.5 = 1/4
    ka = na; kb = nb;
  }

  // prefetch V[0] before softmax to overlap
  uint4 va, vb;
  {
    const unsigned short* vp = VT + (kslice + sE[0]) * 128 + head * 16;
    va = *(const uint4*)vp; vb = *(const uint4*)(vp + 8);
  }

  float m = lg[0];
#pragma unroll
  for (int j = 1; j < 8; ++j) m = fmaxf(m, lg[j]);
  float p[8], sum = 0.f;
#pragma unroll
  for (int j = 0; j < 8; ++j) { p[j] = __expf(lg[j] - m); sum += p[j]; }
  float inv = 1.0f / sum;

  float y[16];
#pragma unroll
  for (int x = 0; x < 16; ++x) y[x] = 0.f;
#pragma unroll
  for (int j = 0; j < 8; ++j) {
    uint4 na, nb;
    if (j < 7) {
      const unsigned short* vp = VT + (kslice + sE[j + 1]) * 128 + head * 16;
      na = *(const uint4*)vp; nb = *(const uint4*)(vp + 8);
    }
    axpy16(va, vb, p[j] * inv, y);
    va = na; vb = nb;
  }

  uint4 o0, o1;
  o0.x = (unsigned)f2bf(y[0]) | ((unsigned)f2bf(y[1]) << 16);
  o0.y = (unsigned)f2bf(y[2]) | ((unsigned)f2bf(y[3]) << 16);
  o0.z = (unsigned)f2bf(y[4]) | ((unsigned)f2bf(y[5]) << 16);
  o0.w = (unsigned)f2bf(y[6]) | ((unsigned)f2bf(y[7]) << 16);
  o1.x = (unsigned)f2bf(y[8]) | ((unsigned)f2bf(y[9]) << 16);
  o1.y = (unsigned)f2bf(y[10]) | ((unsigned)f2bf(y[11]) << 16);
  o1.z = (unsigned)f2bf(y[12]) | ((unsigned)f2bf(y[13]) << 16);
  o1.w = (unsigned)f2bf(y[14]) | ((unsigned)f2bf(y[15]) << 16);
  *(uint4*)(YT + qbase) = o0;
  *(uint4*)(YT + qbase + 8) = o1;
}

// -------------------------------------------------------------------------------
extern "C" void kernel_launch(void* const* d_in, const int* in_sizes, int n_in,
                              void* d_out, int out_size, void* d_ws, size_t ws_size,
                              hipStream_t stream) {
  const float* x  = (const float*)d_in[0];
  const float* wq = (const float*)d_in[1];
  const float* bq = (const float*)d_in[2];
  const float* wk = (const float*)d_in[3];
  const float* bk = (const float*)d_in[4];
  const float* wv = (const float*)d_in[5];
  const float* bv = (const float*)d_in[6];
  const float* wp = (const float*)d_in[7];
  const float* bp = (const float*)d_in[8];

  char* ws = (char*)d_ws;
  unsigned short* Wr = (unsigned short*)ws;       // 4*49152 bf16 = 393216 B
  float* biasf = (float*)(ws + 393216);           // 4*128 f32   = 2048 B
  size_t off = 395264;
  const size_t TENB = (size_t)16 * S_SP * 128 * 2;  // 67108864 B per tensor
  unsigned short* xT = (unsigned short*)(ws + off); off += TENB;
  unsigned short* QT = (unsigned short*)(ws + off); off += TENB;
  unsigned short* KT = (unsigned short*)(ws + off); off += TENB;
  unsigned short* VT = (unsigned short*)(ws + off); off += TENB;
  unsigned short* YT = xT;  // xT dead after QKV convs; reuse for attention out

  // 1) repack weights / biases (fp32 -> bf16 / fp32)
  hipLaunchKernelGGL(repack_kernel, dim3(770), dim3(256), 0, stream,
                     wq, wk, wv, wp, bq, bk, bv, bp, Wr, biasf);
  // 2) x fp32 [c][s] -> xT bf16 [s][c]
  hipLaunchKernelGGL(transpose_f2b_kernel, dim3(256, 2, 16), dim3(256), 0, stream,
                     x, xT, 128, 16384);
  // 3) fused Q,K,V convs (z-loop inside; one LDS stage, one barrier per block)
  conv_kernel<3, false><<<dim3(256, 16), dim3(256), 0, stream>>>(
      xT, Wr, biasf, QT, nullptr);
  // 4) fused both-direction window attention -> YT
  hipLaunchKernelGGL(attn_kernel, dim3(1024, 8), dim3(256), 0, stream,
                     QT, KT, VT, YT);
  // 5) projection conv, fp32 [o][s] epilogue straight into d_out
  conv_kernel<1, true><<<dim3(256, 16), dim3(256), 0, stream>>>(
      YT, Wr + 3 * 49152, biasf + 384, nullptr, (float*)d_out);
}